// Round 3
// baseline (1295.259 us; speedup 1.0000x reference)
//
#include <hip/hip_runtime.h>
#include <hip/hip_bf16.h>

// Problem constants (OutlookAttention, VOLO-style)
#define DIM   384
#define HEADS 12
#define HD    32          // head dim = DIM/HEADS
#define K2    9           // kernel_size^2
#define HH    56
#define WW    56
#define HWP   (HH*WW)     // 3136
#define BB    8
#define AO    (K2*K2*HEADS) // 972 attention-logit channels

typedef __hip_bfloat16 bf16;

static __device__ __forceinline__ float b2f(bf16 v) { return __bfloat162float(v); }

static __device__ __forceinline__ void store_val(float* p, float v) { *p = v; }
static __device__ __forceinline__ void store_val(bf16* p, float v) { *p = __float2bfloat16(v); }
static __device__ __forceinline__ float load_val(const float* p) { return *p; }
static __device__ __forceinline__ float load_val(const bf16* p) { return __bfloat162float(*p); }

// ---------------------------------------------------------------------------
// conv1x1: out[b][o][p] = sum_c in[b][c][p] * w[o][c] (+ bias[o])
// One wave (64 threads) per block: 64 consecutive pixels, OPT output channels
// per thread. w index is wave-uniform -> compiler scalarizes to s_load.
// ---------------------------------------------------------------------------
template<typename TIN, typename TOUT, int OPT, bool BIAS>
__global__ __launch_bounds__(64) void conv1x1_kernel(
        const TIN* __restrict__ in, const float* __restrict__ w,
        const float* __restrict__ bias, TOUT* __restrict__ out, int Cout) {
    const int p  = blockIdx.x * 64 + threadIdx.x;   // pixel within image
    const int ob = blockIdx.y * OPT;                // first output channel
    const int b  = blockIdx.z;

    const TIN*   inp = in + (size_t)b * DIM * HWP + p;
    const float* wp  = w + (size_t)ob * DIM;

    float acc[OPT];
#pragma unroll
    for (int j = 0; j < OPT; j++) acc[j] = 0.f;

#pragma unroll 4
    for (int c = 0; c < DIM; c++) {
        float xv = load_val(&inp[(size_t)c * HWP]);
#pragma unroll
        for (int j = 0; j < OPT; j++)
            acc[j] += xv * wp[j * DIM + c];
    }

#pragma unroll
    for (int j = 0; j < OPT; j++) {
        float r = acc[j];
        if (BIAS) r += bias[ob + j];
        store_val(&out[((size_t)b * Cout + ob + j) * HWP + p], r);
    }
}

// ---------------------------------------------------------------------------
// Fused softmax + attention-apply + fold (as a GATHER, not scatter).
// final[b,c,Y,X] = sum_{i=(ir,ic) valid} sum_d softmax_d(logits[b,(i*9+d)*12+n, yi,xi])
//                                         * v[b,c, yi+dr-1, xi+dc-1]
// with yi = Y+1-ir, xi = X+1-ic, n = c/32. Each softmax row is consumed by
// exactly one output pixel, so nothing extra is materialized.
// ---------------------------------------------------------------------------
__global__ __launch_bounds__(256) void attn_fold_kernel(
        const bf16* __restrict__ logits, const bf16* __restrict__ v,
        bf16* __restrict__ canvas) {
    const int idx = blockIdx.x * 256 + threadIdx.x;
    const int X = idx % WW;
    const int Y = (idx / WW) % HH;
    const int c = (idx / HWP) % DIM;
    const int b = idx / (HWP * DIM);
    const int n = c >> 5;   // head

    const bf16* lg_b = logits + (size_t)b * AO * HWP;
    const bf16* v_bc = v + ((size_t)b * DIM + c) * HWP;

    float total = 0.f;
#pragma unroll
    for (int ir = 0; ir < 3; ir++) {
        const int yi = Y + 1 - ir;
        if (yi < 0 || yi >= HH) continue;
#pragma unroll
        for (int ic = 0; ic < 3; ic++) {
            const int xi = X + 1 - ic;
            if (xi < 0 || xi >= WW) continue;
            const int i = ir * 3 + ic;
            // load 9 logits for this (pixel, head, i)
            float lv[K2];
            float m = -1e30f;
#pragma unroll
            for (int d = 0; d < K2; d++) {
                lv[d] = b2f(lg_b[(size_t)(i * 108 + d * 12 + n) * HWP + yi * WW + xi]);
                m = fmaxf(m, lv[d]);
            }
            float s = 0.f;
#pragma unroll
            for (int d = 0; d < K2; d++) { lv[d] = __expf(lv[d] - m); s += lv[d]; }
            const float inv = 1.f / s;

            float acc = 0.f;
#pragma unroll
            for (int dr = 0; dr < 3; dr++) {
                const int yv = yi + dr - 1;
                if (yv < 0 || yv >= HH) continue;
#pragma unroll
                for (int dc = 0; dc < 3; dc++) {
                    const int xv = xi + dc - 1;
                    if (xv < 0 || xv >= WW) continue;
                    acc += lv[dr * 3 + dc] * b2f(v_bc[yv * WW + xv]);
                }
            }
            total += acc * inv;
        }
    }
    canvas[idx] = __float2bfloat16(total);
}

// ---------------------------------------------------------------------------
extern "C" void kernel_launch(void* const* d_in, const int* in_sizes, int n_in,
                              void* d_out, int out_size, void* d_ws, size_t ws_size,
                              hipStream_t stream) {
    // Reference dtypes: all inputs float32, output float32.
    const float* x      = (const float*)d_in[0];  // [B,384,56,56]
    const float* v_w    = (const float*)d_in[1];  // [384,384]
    const float* v_b    = (const float*)d_in[2];  // [384]
    const float* attn_w = (const float*)d_in[3];  // [972,384]
    const float* proj_w = (const float*)d_in[4];  // [384,384]
    float* out = (float*)d_out;

    const size_t VSZ = (size_t)BB * DIM * HWP;   // 9,633,792
    const size_t LSZ = (size_t)BB * AO  * HWP;   // 24,385,536
    char* ws = (char*)d_ws;
    bf16* vbuf   = (bf16*)ws;                                    // value projection
    bf16* lbuf   = (bf16*)(ws + sizeof(bf16) * VSZ);             // attention logits
    bf16* canvas = (bf16*)(ws + sizeof(bf16) * (VSZ + LSZ));     // pre-proj folded

    // 1) value projection (384 -> 384, +bias)
    dim3 g1(HWP / 64, DIM / 12, BB);
    conv1x1_kernel<float, bf16, 12, true><<<g1, 64, 0, stream>>>(x, v_w, v_b, vbuf, DIM);

    // 2) attention logits (384 -> 972)
    dim3 g2(HWP / 64, AO / 12, BB);
    conv1x1_kernel<float, bf16, 12, false><<<g2, 64, 0, stream>>>(x, attn_w, nullptr, lbuf, AO);

    // 3) fused softmax + attend + fold (gather form)
    attn_fold_kernel<<<(int)(VSZ / 256), 256, 0, stream>>>(lbuf, vbuf, canvas);

    // 4) output projection (384 -> 384), reads bf16 canvas, writes fp32 out
    dim3 g3(HWP / 64, DIM / 12, BB);
    conv1x1_kernel<bf16, float, 12, false><<<g3, 64, 0, stream>>>(canvas, proj_w, nullptr, out, DIM);
}

// Round 5
// 603.537 us; speedup vs baseline: 2.1461x; 2.1461x over previous
//
#include <hip/hip_runtime.h>
#include <hip/hip_bf16.h>

#define DIM   384
#define HEADS 12
#define K2    9
#define HH    56
#define WW    56
#define HWP   3136
#define BB    8
#define AO    972      // attn-logit channels
#define AOP   1024     // padded to 128
#define PP    3200     // pixels padded to 25*128

typedef __hip_bfloat16 bf16;
typedef short bf16x8 __attribute__((ext_vector_type(8)));
typedef short bf16x4v __attribute__((ext_vector_type(4)));
typedef float f32x4 __attribute__((ext_vector_type(4)));

static __device__ __forceinline__ float b2f(bf16 v) { return __bfloat162float(v); }
static __device__ __forceinline__ short f2bs(float f) {
    __hip_bfloat16 h = __float2bfloat16(f);
    return *(short*)&h;
}

// async global->LDS, 16B per lane. LDS dest must be wave-uniform base + lane*16.
static __device__ __forceinline__ void gl_lds16(const bf16* g, bf16* l) {
    __builtin_amdgcn_global_load_lds(
        (const __attribute__((address_space(1))) unsigned int*)g,
        (__attribute__((address_space(3))) unsigned int*)l, 16, 0, 0);
}

// ---------------------------------------------------------------------------
// x [b][384][3136] fp32  ->  xT [b][3200][384] bf16 (zero pad rows)
// ---------------------------------------------------------------------------
__global__ __launch_bounds__(256) void xpose_kernel(
        const float* __restrict__ x, bf16* __restrict__ xT) {
    const int lane = threadIdx.x & 63, w = threadIdx.x >> 6;
    const int p = blockIdx.x * 64 + lane;
    const int b = blockIdx.y;
    bf16* dst = xT + ((size_t)b * PP + p) * DIM;
    if (p >= HWP) {
        bf16x8 z = {};
        for (int cg = w; cg < 48; cg += 4) *(bf16x8*)(dst + cg * 8) = z;
        return;
    }
    const float* src = x + (size_t)b * DIM * HWP + p;
    for (int cg = w; cg < 48; cg += 4) {
        bf16x8 v;
#pragma unroll
        for (int j = 0; j < 8; j++) v[j] = f2bs(src[(size_t)(cg * 8 + j) * HWP]);
        *(bf16x8*)(dst + cg * 8) = v;
    }
}

// weights fp32 [rows][384] -> bf16 [rows_pad][384], zero pad rows
__global__ __launch_bounds__(256) void wconv_kernel(
        const float* __restrict__ src, bf16* __restrict__ dst, int rows, int rows_pad) {
    int idx = blockIdx.x * 256 + threadIdx.x;
    if (idx >= rows_pad * DIM) return;
    float v = (idx < rows * DIM) ? src[idx] : 0.f;
    *(short*)&dst[idx] = f2bs(v);
}

// ---------------------------------------------------------------------------
// GEMM: out = A[M_pad][384] x Bt^T where Bt [b][PP][384] (k-contiguous rows).
// 128(M) x 128(N) tile, BK=32, 4 waves each 64x64 (4x4 16x16x32 MFMA).
// OUT_T=false: planar out [b][M_out][3136] (TOUT bf16/float), no bias.
// OUT_T=true : bf16 out [b][PP][DIM] (vT) via LDS-repack epilogue, +bias.
// ---------------------------------------------------------------------------
template<bool OUT_T, typename TOUT>
__global__ __launch_bounds__(256) void gemm_kernel(
        const bf16* __restrict__ A, const bf16* __restrict__ Bt,
        const float* __restrict__ bias, TOUT* __restrict__ out, int M_out) {
    __shared__ bf16 lds[8192];          // lA 4096 | lB 4096
    bf16* lA = lds;
    bf16* lB = lds + 4096;
    const int t = threadIdx.x;
    const int lane = t & 63, w = t >> 6;
    const int wm = w & 1, wn = w >> 1;
    const int quad = lane >> 4, l16 = lane & 15;
    const int n0 = blockIdx.x * 128;
    const int m0 = blockIdx.y * 128;
    const int b = blockIdx.z;

    const bf16* Ab = A + (size_t)m0 * DIM;
    const bf16* Bb = Bt + ((size_t)b * PP + n0) * DIM;

    f32x4 acc[4][4] = {};

    for (int k0 = 0; k0 < DIM; k0 += 32) {
#pragma unroll
        for (int r = 0; r < 2; r++) {
            int idx = r * 256 + t;
            gl_lds16(Ab + (size_t)(idx >> 2) * DIM + k0 + (idx & 3) * 8, lA + idx * 8);
        }
#pragma unroll
        for (int r = 0; r < 2; r++) {
            int idx = r * 256 + t;
            gl_lds16(Bb + (size_t)(idx >> 2) * DIM + k0 + (idx & 3) * 8, lB + idx * 8);
        }
        __syncthreads();
        bf16x8 af[4], bfr[4];
#pragma unroll
        for (int mt = 0; mt < 4; mt++)
            af[mt] = *(const bf16x8*)(lA + (wm * 64 + mt * 16 + l16) * 32 + quad * 8);
#pragma unroll
        for (int nt = 0; nt < 4; nt++)
            bfr[nt] = *(const bf16x8*)(lB + (wn * 64 + nt * 16 + l16) * 32 + quad * 8);
#pragma unroll
        for (int mt = 0; mt < 4; mt++)
#pragma unroll
            for (int nt = 0; nt < 4; nt++)
                acc[mt][nt] = __builtin_amdgcn_mfma_f32_16x16x32_bf16(
                    af[mt], bfr[nt], acc[mt][nt], 0, 0, 0);
        __syncthreads();
    }

    if constexpr (!OUT_T) {
        // planar [b][M_out][3136]; C/D: row(m)=quad*4+reg, col(n)=l16
#pragma unroll
        for (int mt = 0; mt < 4; mt++) {
#pragma unroll
            for (int nt = 0; nt < 4; nt++) {
                int p = n0 + wn * 64 + nt * 16 + l16;
                if (p >= HWP) continue;
#pragma unroll
                for (int reg = 0; reg < 4; reg++) {
                    int o = m0 + wm * 64 + mt * 16 + quad * 4 + reg;
                    if (o < M_out) {
                        TOUT* dp = out + ((size_t)b * M_out + o) * HWP + p;
                        if constexpr (sizeof(TOUT) == 2)
                            *(short*)dp = f2bs(acc[mt][nt][reg]);
                        else
                            *(float*)dp = acc[mt][nt][reg];
                    }
                }
            }
        }
    } else {
        // vT [b][PP][DIM] bf16 with bias; repack 64x64 wave tile via LDS,
        // row stride 72 bf16 (conflict-free, 16B aligned)
        bf16* wbuf = lds + w * 1152;
#pragma unroll
        for (int nt = 0; nt < 4; nt++) {
#pragma unroll
            for (int mt = 0; mt < 4; mt++) {
                float4 bi = *(const float4*)(bias + m0 + wm * 64 + mt * 16 + quad * 4);
                bf16x4v pk;
                pk[0] = f2bs(acc[mt][nt][0] + bi.x);
                pk[1] = f2bs(acc[mt][nt][1] + bi.y);
                pk[2] = f2bs(acc[mt][nt][2] + bi.z);
                pk[3] = f2bs(acc[mt][nt][3] + bi.w);
                *(bf16x4v*)(wbuf + l16 * 72 + mt * 16 + quad * 4) = pk;
            }
            __syncthreads();
            int nr = lane >> 2;
            int mc = (lane & 3) * 16;
            bf16x8 v0 = *(const bf16x8*)(wbuf + nr * 72 + mc);
            bf16x8 v1 = *(const bf16x8*)(wbuf + nr * 72 + mc + 8);
            int p = n0 + wn * 64 + nt * 16 + nr;
            if (p < HWP) {
                bf16* dp = (bf16*)out + ((size_t)b * PP + p) * DIM + m0 + wm * 64 + mc;
                *(bf16x8*)dp = v0;
                *(bf16x8*)(dp + 8) = v1;
            }
            __syncthreads();
        }
    }
}

// ---------------------------------------------------------------------------
// Block per (pixel, b): 384 threads.
// Phase 1: 108 threads (i=0..8, n=0..11) compute softmax over d of the
//   logits AT THE WINDOW CENTER (yi,xi) = (Y+1-ir, X+1-ic)  <-- round-4 bug
//   was computing all 81 softmaxes at (Y,X). Out-of-range centers -> P=0.
// Phase 2: thread=c accumulates sum_i sum_d P[i][n][d] * vT[(yi+dr-1, xi+dc-1)][c].
// ---------------------------------------------------------------------------
__global__ __launch_bounds__(384) void attn_fold_kernel(
        const bf16* __restrict__ lg, const bf16* __restrict__ vT,
        bf16* __restrict__ cT) {
    __shared__ float P[9 * 12 * 12];    // [i][n][d pad 12]
    const int t = threadIdx.x;
    const int pix = blockIdx.x;
    const int b = blockIdx.y;
    const int X = pix % WW, Y = pix / WW;

    if (t < 108) {
        const int i = t / 12, n = t % 12;
        const int ir = i / 3, ic = i % 3;
        const int yi = Y + 1 - ir, xi = X + 1 - ic;
        float* Pd = &P[(i * 12 + n) * 12];
        if (yi < 0 || yi >= HH || xi < 0 || xi >= WW) {
#pragma unroll
            for (int d = 0; d < K2; d++) Pd[d] = 0.f;
        } else {
            const bf16* base = lg + ((size_t)b * AO + i * 12 * K2 + n) * HWP + yi * WW + xi;
            float lv[K2];
            float m = -1e30f;
#pragma unroll
            for (int d = 0; d < K2; d++) {
                lv[d] = b2f(base[(size_t)d * 12 * HWP]);
                m = fmaxf(m, lv[d]);
            }
            float s = 0.f;
#pragma unroll
            for (int d = 0; d < K2; d++) { lv[d] = __expf(lv[d] - m); s += lv[d]; }
            const float inv = 1.f / s;
#pragma unroll
            for (int d = 0; d < K2; d++) Pd[d] = lv[d] * inv;
        }
    }
    __syncthreads();

    const int c = t;
    const int n = c >> 5;
    const bf16* vb = vT + (size_t)b * PP * DIM + c;
    float acc = 0.f;
#pragma unroll
    for (int ir = 0; ir < 3; ir++) {
        const int yi = Y + 1 - ir;
        if (yi < 0 || yi >= HH) continue;
#pragma unroll
        for (int ic = 0; ic < 3; ic++) {
            const int xi = X + 1 - ic;
            if (xi < 0 || xi >= WW) continue;
            const float* Pr = &P[((ir * 3 + ic) * 12 + n) * 12];
#pragma unroll
            for (int dr = 0; dr < 3; dr++) {
                const int yv = yi + dr - 1;
                if (yv < 0 || yv >= HH) continue;
#pragma unroll
                for (int dc = 0; dc < 3; dc++) {
                    const int xv = xi + dc - 1;
                    if (xv < 0 || xv >= WW) continue;
                    acc += Pr[dr * 3 + dc] * b2f(vb[(size_t)(yv * WW + xv) * DIM]);
                }
            }
        }
    }
    cT[((size_t)b * PP + pix) * DIM + c] = __float2bfloat16(acc);
}

// ---------------------------------------------------------------------------
extern "C" void kernel_launch(void* const* d_in, const int* in_sizes, int n_in,
                              void* d_out, int out_size, void* d_ws, size_t ws_size,
                              hipStream_t stream) {
    const float* x      = (const float*)d_in[0];
    const float* v_w    = (const float*)d_in[1];
    const float* v_b    = (const float*)d_in[2];
    const float* attn_w = (const float*)d_in[3];
    const float* proj_w = (const float*)d_in[4];
    float* out = (float*)d_out;

    bf16* xT   = (bf16*)d_ws;                         // [8][3200][384]
    bf16* vT   = xT + (size_t)BB * PP * DIM;          // [8][3200][384]
    bf16* lbuf = vT + (size_t)BB * PP * DIM;          // [8][972][3136]
    bf16* wv   = lbuf + (size_t)BB * AO * HWP;        // [384][384]
    bf16* wa   = wv + 384 * DIM;                      // [1024][384]
    bf16* wp   = wa + AOP * DIM;                      // [384][384]
    bf16* cT   = xT;   // canvasT aliases xT (xT dead after GEMM2)

    wconv_kernel<<<(384 * DIM + 255) / 256, 256, 0, stream>>>(v_w, wv, 384, 384);
    wconv_kernel<<<(AOP * DIM + 255) / 256, 256, 0, stream>>>(attn_w, wa, AO, AOP);
    wconv_kernel<<<(384 * DIM + 255) / 256, 256, 0, stream>>>(proj_w, wp, 384, 384);
    xpose_kernel<<<dim3(PP / 64, BB), 256, 0, stream>>>(x, xT);

    // 1) value projection -> vT (transposed, +bias)
    gemm_kernel<true, bf16><<<dim3(PP / 128, 3, BB), 256, 0, stream>>>(wv, xT, v_b, vT, DIM);
    // 2) attention logits -> lbuf (planar)
    gemm_kernel<false, bf16><<<dim3(PP / 128, AOP / 128, BB), 256, 0, stream>>>(wa, xT, nullptr, lbuf, AO);
    // 3) fused softmax + attend + fold -> canvasT
    attn_fold_kernel<<<dim3(HWP, BB), 384, 0, stream>>>(lbuf, vT, cT);
    // 4) output projection -> out (planar fp32)
    gemm_kernel<false, float><<<dim3(PP / 128, 3, BB), 256, 0, stream>>>(wp, cT, nullptr, out, DIM);
}

// Round 6
// 253.300 us; speedup vs baseline: 5.1135x; 2.3827x over previous
//
#include <hip/hip_runtime.h>
#include <hip/hip_bf16.h>

#define DIM   384
#define HEADS 12
#define K2    9
#define HH    56
#define WW    56
#define HWP   3136
#define BB    8
#define AO    972      // attn-logit channels
#define AOP   1024     // padded to 128 (and lT row stride)
#define PP    3200     // pixels padded to 25*128

typedef __hip_bfloat16 bf16;
typedef short bf16x8 __attribute__((ext_vector_type(8)));
typedef short bf16x4v __attribute__((ext_vector_type(4)));
typedef float f32x4 __attribute__((ext_vector_type(4)));

static __device__ __forceinline__ float b2f(bf16 v) { return __bfloat162float(v); }
static __device__ __forceinline__ float bs2f(short s) {
    return __uint_as_float(((unsigned int)(unsigned short)s) << 16);
}
static __device__ __forceinline__ short f2bs(float f) {
    __hip_bfloat16 h = __float2bfloat16(f);
    return *(short*)&h;
}

// async global->LDS, 16B per lane. LDS dest must be wave-uniform base + lane*16.
static __device__ __forceinline__ void gl_lds16(const bf16* g, bf16* l) {
    __builtin_amdgcn_global_load_lds(
        (const __attribute__((address_space(1))) unsigned int*)g,
        (__attribute__((address_space(3))) unsigned int*)l, 16, 0, 0);
}

// ---------------------------------------------------------------------------
// x [b][384][3136] fp32  ->  xT [b][3200][384] bf16 (zero pad rows)
// ---------------------------------------------------------------------------
__global__ __launch_bounds__(256) void xpose_kernel(
        const float* __restrict__ x, bf16* __restrict__ xT) {
    const int lane = threadIdx.x & 63, w = threadIdx.x >> 6;
    const int p = blockIdx.x * 64 + lane;
    const int b = blockIdx.y;
    bf16* dst = xT + ((size_t)b * PP + p) * DIM;
    if (p >= HWP) {
        bf16x8 z = {};
        for (int cg = w; cg < 48; cg += 4) *(bf16x8*)(dst + cg * 8) = z;
        return;
    }
    const float* src = x + (size_t)b * DIM * HWP + p;
    for (int cg = w; cg < 48; cg += 4) {
        bf16x8 v;
#pragma unroll
        for (int j = 0; j < 8; j++) v[j] = f2bs(src[(size_t)(cg * 8 + j) * HWP]);
        *(bf16x8*)(dst + cg * 8) = v;
    }
}

// weights fp32 [rows][384] -> bf16 [rows_pad][384], zero pad rows
__global__ __launch_bounds__(256) void wconv_kernel(
        const float* __restrict__ src, bf16* __restrict__ dst, int rows, int rows_pad) {
    int idx = blockIdx.x * 256 + threadIdx.x;
    if (idx >= rows_pad * DIM) return;
    float v = (idx < rows * DIM) ? src[idx] : 0.f;
    *(short*)&dst[idx] = f2bs(v);
}

// ---------------------------------------------------------------------------
// GEMM: out = A[M_pad][384] x Bt^T where Bt [b][PP][384] (k-contiguous rows).
// 128(M) x 128(N) tile, BK=32, 4 waves each 64x64 (4x4 16x16x32 MFMA).
// OUT_T=false: planar out [b][M_out][3136] (TOUT float), no bias.
// OUT_T=true : bf16 out [b][PP][OSTR] via LDS-repack epilogue, optional bias.
// ---------------------------------------------------------------------------
template<bool OUT_T, bool BIAS, int OSTR, typename TOUT>
__global__ __launch_bounds__(256) void gemm_kernel(
        const bf16* __restrict__ A, const bf16* __restrict__ Bt,
        const float* __restrict__ bias, TOUT* __restrict__ out, int M_out) {
    __shared__ bf16 lds[8192];          // lA 4096 | lB 4096
    bf16* lA = lds;
    bf16* lB = lds + 4096;
    const int t = threadIdx.x;
    const int lane = t & 63, w = t >> 6;
    const int wm = w & 1, wn = w >> 1;
    const int quad = lane >> 4, l16 = lane & 15;
    const int n0 = blockIdx.x * 128;
    const int m0 = blockIdx.y * 128;
    const int b = blockIdx.z;

    const bf16* Ab = A + (size_t)m0 * DIM;
    const bf16* Bb = Bt + ((size_t)b * PP + n0) * DIM;

    f32x4 acc[4][4] = {};

    for (int k0 = 0; k0 < DIM; k0 += 32) {
#pragma unroll
        for (int r = 0; r < 2; r++) {
            int idx = r * 256 + t;
            gl_lds16(Ab + (size_t)(idx >> 2) * DIM + k0 + (idx & 3) * 8, lA + idx * 8);
        }
#pragma unroll
        for (int r = 0; r < 2; r++) {
            int idx = r * 256 + t;
            gl_lds16(Bb + (size_t)(idx >> 2) * DIM + k0 + (idx & 3) * 8, lB + idx * 8);
        }
        __syncthreads();
        bf16x8 af[4], bfr[4];
#pragma unroll
        for (int mt = 0; mt < 4; mt++)
            af[mt] = *(const bf16x8*)(lA + (wm * 64 + mt * 16 + l16) * 32 + quad * 8);
#pragma unroll
        for (int nt = 0; nt < 4; nt++)
            bfr[nt] = *(const bf16x8*)(lB + (wn * 64 + nt * 16 + l16) * 32 + quad * 8);
#pragma unroll
        for (int mt = 0; mt < 4; mt++)
#pragma unroll
            for (int nt = 0; nt < 4; nt++)
                acc[mt][nt] = __builtin_amdgcn_mfma_f32_16x16x32_bf16(
                    af[mt], bfr[nt], acc[mt][nt], 0, 0, 0);
        __syncthreads();
    }

    if constexpr (!OUT_T) {
        // planar [b][M_out][3136]; C/D: row(m)=quad*4+reg, col(n)=l16
#pragma unroll
        for (int mt = 0; mt < 4; mt++) {
#pragma unroll
            for (int nt = 0; nt < 4; nt++) {
                int p = n0 + wn * 64 + nt * 16 + l16;
                if (p >= HWP) continue;
#pragma unroll
                for (int reg = 0; reg < 4; reg++) {
                    int o = m0 + wm * 64 + mt * 16 + quad * 4 + reg;
                    if (o < M_out)
                        out[((size_t)b * M_out + o) * HWP + p] = (TOUT)acc[mt][nt][reg];
                }
            }
        }
    } else {
        // out [b][PP][OSTR] bf16 (+bias); repack 64x64 wave tile via LDS,
        // row stride 72 bf16 (conflict-free, 16B aligned)
        bf16* wbuf = lds + w * 1152;
#pragma unroll
        for (int nt = 0; nt < 4; nt++) {
#pragma unroll
            for (int mt = 0; mt < 4; mt++) {
                float4 bi;
                if constexpr (BIAS) bi = *(const float4*)(bias + m0 + wm * 64 + mt * 16 + quad * 4);
                else bi = make_float4(0.f, 0.f, 0.f, 0.f);
                bf16x4v pk;
                pk[0] = f2bs(acc[mt][nt][0] + bi.x);
                pk[1] = f2bs(acc[mt][nt][1] + bi.y);
                pk[2] = f2bs(acc[mt][nt][2] + bi.z);
                pk[3] = f2bs(acc[mt][nt][3] + bi.w);
                *(bf16x4v*)(wbuf + l16 * 72 + mt * 16 + quad * 4) = pk;
            }
            __syncthreads();
            int nr = lane >> 2;
            int mc = (lane & 3) * 16;
            bf16x8 v0 = *(const bf16x8*)(wbuf + nr * 72 + mc);
            bf16x8 v1 = *(const bf16x8*)(wbuf + nr * 72 + mc + 8);
            int p = n0 + wn * 64 + nt * 16 + nr;
            if (p < HWP) {
                bf16* dp = (bf16*)out + ((size_t)b * PP + p) * OSTR + m0 + wm * 64 + mc;
                *(bf16x8*)dp = v0;
                *(bf16x8*)(dp + 8) = v1;
            }
            __syncthreads();
        }
    }
}

// ---------------------------------------------------------------------------
// attn+fold, 8 pixels (one row segment) per block, 384 threads.
// Stage A: 864 softmaxes (8 px x 9 windows x 12 heads) from lT -> P in LDS.
//   Window i's softmax is taken at the window CENTER (yi,xi)=(Y+1-ir, X+px+1-ic);
//   invalid centers -> P=0.
// Stage B: reduce 81 taps to 25 effective weights per (px, head):
//   W[dy+2][dx+2] = sum_{dr-ir=dy, dc-ic=dx} P[i][n][d]
// Stage C: apply 5x5 gather: out[c] += W[off][n] * v[Y+dy][X+dx][c],
//   bf16x8 loads (48 thr/pixel), neighbor-invalid -> weight 0 (clamped addr).
// ---------------------------------------------------------------------------
__global__ __launch_bounds__(384) void attn_fold_kernel(
        const bf16* __restrict__ lT, const bf16* __restrict__ vT,
        bf16* __restrict__ cT) {
    __shared__ float P[8 * 9 * 12 * 10];   // [px][i][n][d pad10]  34560 B
    __shared__ float Wf[8 * 25 * 12];      // [px][off][n]          9600 B
    const int t = threadIdx.x;
    const int b = blockIdx.y;
    const int pix0 = blockIdx.x * 8;
    const int Y = pix0 / WW, X0 = pix0 % WW;

    // ---- stage A
    for (int r = t; r < 864; r += 384) {
        const int px = r / 108, rem = r % 108;
        const int i = rem / 12, n = rem % 12;
        const int ir = i / 3, ic = i % 3;
        const int yi = Y + 1 - ir, xi = X0 + px + 1 - ic;
        float* Pd = &P[((px * 9 + i) * 12 + n) * 10];
        if (yi < 0 || yi >= HH || xi < 0 || xi >= WW) {
#pragma unroll
            for (int d = 0; d < K2; d++) Pd[d] = 0.f;
        } else {
            const bf16* base = lT + ((size_t)b * PP + yi * WW + xi) * AOP + i * 108 + n;
            float lv[K2];
            float m = -1e30f;
#pragma unroll
            for (int d = 0; d < K2; d++) {
                lv[d] = b2f(base[d * 12]);
                m = fmaxf(m, lv[d]);
            }
            float s = 0.f;
#pragma unroll
            for (int d = 0; d < K2; d++) { lv[d] = __expf(lv[d] - m); s += lv[d]; }
            const float inv = 1.f / s;
#pragma unroll
            for (int d = 0; d < K2; d++) Pd[d] = lv[d] * inv;
        }
    }
    __syncthreads();

    // ---- stage B
    for (int e = t; e < 2400; e += 384) {
        const int px = e / 300, rem = e % 300;
        const int off = rem / 12, n = rem % 12;
        const int dy = off / 5 - 2, dx = off % 5 - 2;
        const int ir_lo = max(0, -dy), ir_hi = min(2, 2 - dy);
        const int ic_lo = max(0, -dx), ic_hi = min(2, 2 - dx);
        float wsum = 0.f;
        for (int ir = ir_lo; ir <= ir_hi; ir++)
            for (int ic = ic_lo; ic <= ic_hi; ic++) {
                const int i = ir * 3 + ic;
                const int d = (dy + ir) * 3 + (dx + ic);
                wsum += P[((px * 9 + i) * 12 + n) * 10 + d];
            }
        Wf[e] = wsum;  // e == (px*25 + off)*12 + n
    }
    __syncthreads();

    // ---- stage C
    const int px = t / 48, cg = t % 48;
    const int X = X0 + px;
    const int n = cg >> 2;                  // head = (cg*8)/32
    const float* Wp = &Wf[px * 300];
    const bf16* vb = vT + (size_t)b * PP * DIM;
    float acc[8] = {};
#pragma unroll
    for (int dy = -2; dy <= 2; dy++) {
        const int ny = Y + dy;              // block-uniform branch
        if (ny < 0 || ny >= HH) continue;
#pragma unroll
        for (int dx = -2; dx <= 2; dx++) {
            const int nx = X + dx;
            const bool ok = (nx >= 0 && nx < WW);
            const int nxc = min(max(nx, 0), WW - 1);
            const float w = ok ? Wp[((dy + 2) * 5 + dx + 2) * 12 + n] : 0.f;
            bf16x8 vv = *(const bf16x8*)(vb + (size_t)(ny * WW + nxc) * DIM + cg * 8);
#pragma unroll
            for (int j = 0; j < 8; j++) acc[j] += w * bs2f(vv[j]);
        }
    }
    bf16x8 po;
#pragma unroll
    for (int j = 0; j < 8; j++) po[j] = f2bs(acc[j]);
    *(bf16x8*)(cT + ((size_t)b * PP + pix0 + px) * DIM + cg * 8) = po;
}

// ---------------------------------------------------------------------------
extern "C" void kernel_launch(void* const* d_in, const int* in_sizes, int n_in,
                              void* d_out, int out_size, void* d_ws, size_t ws_size,
                              hipStream_t stream) {
    const float* x      = (const float*)d_in[0];
    const float* v_w    = (const float*)d_in[1];
    const float* v_b    = (const float*)d_in[2];
    const float* attn_w = (const float*)d_in[3];
    const float* proj_w = (const float*)d_in[4];
    float* out = (float*)d_out;

    bf16* xT   = (bf16*)d_ws;                         // [8][3200][384]
    bf16* vT   = xT + (size_t)BB * PP * DIM;          // [8][3200][384]
    bf16* lT   = vT + (size_t)BB * PP * DIM;          // [8][3200][1024]
    bf16* wv   = lT + (size_t)BB * PP * AOP;          // [384][384]
    bf16* wa   = wv + 384 * DIM;                      // [1024][384]
    bf16* wp   = wa + AOP * DIM;                      // [384][384]
    bf16* cT   = xT;   // canvasT aliases xT (xT dead after GEMM2)

    wconv_kernel<<<(384 * DIM + 255) / 256, 256, 0, stream>>>(v_w, wv, 384, 384);
    wconv_kernel<<<(AOP * DIM + 255) / 256, 256, 0, stream>>>(attn_w, wa, AO, AOP);
    wconv_kernel<<<(384 * DIM + 255) / 256, 256, 0, stream>>>(proj_w, wp, 384, 384);
    xpose_kernel<<<dim3(PP / 64, BB), 256, 0, stream>>>(x, xT);

    // 1) value projection -> vT [b][PP][384] (+bias)
    gemm_kernel<true, true, DIM, bf16><<<dim3(PP / 128, 3, BB), 256, 0, stream>>>(wv, xT, v_b, vT, DIM);
    // 2) attention logits -> lT [b][PP][1024] (transposed)
    gemm_kernel<true, false, AOP, bf16><<<dim3(PP / 128, AOP / 128, BB), 256, 0, stream>>>(wa, xT, nullptr, lT, AOP);
    // 3) fused softmax + weight-reduce + 5x5 gather -> cT
    attn_fold_kernel<<<dim3(HWP / 8, BB), 384, 0, stream>>>(lT, vT, cT);
    // 4) output projection -> out (planar fp32)
    gemm_kernel<false, false, 0, float><<<dim3(PP / 128, 3, BB), 256, 0, stream>>>(wp, cT, nullptr, out, DIM);
}